// Round 11
// baseline (329.315 us; speedup 1.0000x reference)
//
#include <hip/hip_runtime.h>

typedef unsigned short u16;
typedef unsigned int u32;
typedef __attribute__((ext_vector_type(8))) short short8;
typedef __attribute__((ext_vector_type(4))) float f32x4;

#define AS1 __attribute__((address_space(1)))
#define AS3 __attribute__((address_space(3)))

__device__ __forceinline__ u16 f2bf(float f) {
  union { float f; unsigned u; } v; v.f = f;
  return (u16)((v.u + 0x7fffu + ((v.u >> 16) & 1u)) >> 16);
}
__device__ __forceinline__ u32 pack2bf(float a, float b) {
  return (u32)f2bf(a) | ((u32)f2bf(b) << 16);
}
__device__ __forceinline__ float bf2f(u16 h) {
  union { u32 u; float f; } v; v.u = ((u32)h) << 16; return v.f;
}
// truncating bf16 pack: [b.hi16 : a.hi16] in one v_perm_b32
__device__ __forceinline__ u32 permpack(float a, float b) {
  union { float f; u32 u; } ua, ub; ua.f = a; ub.f = b;
  return __builtin_amdgcn_perm(ub.u, ua.u, 0x07060302u);
}

// Fragment-packed matrix layout (both GEMM operands):
// per (rb, kb): 8 frags x 512 u16; frag f, slot lane*8+e =
//   X[rb*128 + f*16 + (lane&15)][kb*32 + (lane>>4)*8 + e]
// One frag = one contiguous 1KB b128 burst at base+lane*8.
// A 64-K tile of a row-block = 16 KB CONTIGUOUS (kb, kb+1) -> glds-friendly.

// ---------------- pack weights fp32 -> bf16, frag order ----------------
__global__ __launch_bounds__(256)
void packb_kernel(const float* __restrict__ wqkv, const float* __restrict__ wo,
                  const float* __restrict__ w1, const float* __restrict__ w2,
                  u16* __restrict__ oqkv, u16* __restrict__ oo,
                  u16* __restrict__ o1, u16* __restrict__ o2) {
  __shared__ u16 Ls[128][40];
  const int b = blockIdx.x, t = threadIdx.x;
  const float* W; u16* O; int nb, kb, KB; float scale = 1.0f;
  if (b < 768)       { W = wqkv; O = oqkv; KB = 32;  int i2 = b;        nb = i2 >> 5; kb = i2 & 31;
                       if (nb >= 8 && nb < 16) scale = 0.125f; }
  else if (b < 1024) { W = wo;   O = oo;   KB = 32;  int i2 = b - 768;  nb = i2 >> 5; kb = i2 & 31; }
  else if (b < 2048) { W = w1;   O = o1;   KB = 32;  int i2 = b - 1024; nb = i2 >> 5; kb = i2 & 31; }
  else               { W = w2;   O = o2;   KB = 128; int i2 = b - 2048; nb = i2 >> 7; kb = i2 & 127; }
  const int K = KB * 32;
  {
    const int r = t >> 1, c0 = (t & 1) * 16;
    const float* src = W + (size_t)(nb * 128 + r) * K + kb * 32 + c0;
#pragma unroll
    for (int e = 0; e < 16; ++e) Ls[r][c0 + e] = f2bf(src[e] * scale);
  }
  __syncthreads();
  const int f = t >> 5, l0 = (t & 31) * 2;
  u16* dst = O + ((size_t)(nb * KB + kb) * 8 + f) * 512 + (size_t)l0 * 8;
  short8 v0, v1;
#pragma unroll
  for (int e = 0; e < 8; ++e) v0[e] = (short)Ls[f * 16 + (l0 & 15)][(l0 >> 4) * 8 + e];
  const int l1 = l0 + 1;
#pragma unroll
  for (int e = 0; e < 8; ++e) v1[e] = (short)Ls[f * 16 + (l1 & 15)][(l1 >> 4) * 8 + e];
  *(short8*)dst = v0;
  *(short8*)(dst + 8) = v1;
}

// ---------------- RMSNorm: fp32 in -> bf16 A-frag-packed out (D=1024) -------
__global__ void rmsnorm_kernel(const float* __restrict__ x, const float* __restrict__ w,
                               u16* __restrict__ out) {
  const int row = blockIdx.x, tid = threadIdx.x;
  const float4 v = ((const float4*)(x + (size_t)row * 1024))[tid];
  float ss = v.x * v.x + v.y * v.y + v.z * v.z + v.w * v.w;
#pragma unroll
  for (int off = 32; off > 0; off >>= 1) ss += __shfl_xor(ss, off);
  __shared__ float red[4];
  if ((tid & 63) == 0) red[tid >> 6] = ss;
  __syncthreads();
  float tot = red[0] + red[1] + red[2] + red[3];
  float scale = 1.0f / sqrtf(tot * (1.0f / 1024.0f) + 1e-5f);
  const float4 wv = ((const float4*)w)[tid];
  const int kb = tid >> 3, quadp = (tid >> 1) & 3, e0 = (tid & 1) * 4;
  const int mb = row >> 7, i_o = (row >> 4) & 7, l16_o = row & 15;
  size_t off = (((size_t)mb * 32 + kb) * 8 + i_o) * 512 + (quadp * 16 + l16_o) * 8 + e0;
  u32 lo = pack2bf(v.x * scale * wv.x, v.y * scale * wv.y);
  u32 hi = pack2bf(v.z * scale * wv.z, v.w * scale * wv.w);
  *(uint2*)(out + off) = make_uint2(lo, hi);
}

// ---------------- GEMM v4: A frag-packed via glds dbuf LDS, B direct --------
// EPI 0: store bf16 row-major        EPI 1: out_f32 = RES + C (row-major)
// EPI 2: store bf16(gelu(C)) PACKED  EPI 3: bf16 partial row-major (split-K)
// BK=64: per iter 4 glds (A, 16KB contiguous frag-packed region -> perfectly
// coalesced, conflict-free lane*16 LDS reads) + 8 direct packed-B frag loads
// (register-prefetched one iter ahead) + 32 MFMA per barrier (2x R9).
template <int EPI>
__global__ __launch_bounds__(256, 3)
void gemm_pp(const u16* __restrict__ Ap, const u16* __restrict__ Bp,
             const float* __restrict__ RES, void* __restrict__ OUT,
             int M, int N, int K, int KS) {
  __shared__ __align__(16) u16 As[2][8192];   // 2 x 16 KB
  const int tid = threadIdx.x;
  const int wave = tid >> 6, lane = tid & 63;
  const int quad = lane >> 4, l16 = lane & 15;
  int bx = blockIdx.x, by = blockIdx.y;
  const int gx = gridDim.x, gy = gridDim.y;
  if (((gx & 1) | (gy & 3)) == 0) {          // XCD-region remap (R9)
    const int lin = blockIdx.x + gx * blockIdx.y;
    const int xcd = lin & 7, j = lin >> 3;
    const int rw = gx >> 1;
    bx = (xcd & 1) * rw + j % rw;
    by = (xcd >> 1) * (gy >> 2) + j / rw;
  }
  const int wm = (wave >> 1) * 64, wn = (wave & 1) * 64;
  const int KB = K >> 5;
  f32x4 acc[4][4] = {};

  const int kb0 = (blockIdx.z * KS) >> 5;
  const int nit = KS >> 6;                    // 64-K iterations
  // A: contiguous 16KB per iter; each wave stages its 4KB quarter
  const u16* Ag = Ap + ((size_t)by * KB + kb0) * 4096 + wave * 2048 + lane * 8;
  // B: direct packed frags (wn selects frag group)
  const u16* Bw = Bp + (((size_t)bx * KB + kb0) * 8 + (wn >> 4)) * 512 + (size_t)lane * 8;

  auto stage = [&](int it, int pp) {
    const u16* s = Ag + (size_t)it * 8192;
    u16* d = &As[pp][wave * 2048];
    __builtin_amdgcn_global_load_lds((AS1 void*)s, (AS3 void*)d, 16, 0, 0);
    __builtin_amdgcn_global_load_lds((AS1 void*)(s + 512), (AS3 void*)(d + 512), 16, 0, 0);
    __builtin_amdgcn_global_load_lds((AS1 void*)(s + 1024), (AS3 void*)(d + 1024), 16, 0, 0);
    __builtin_amdgcn_global_load_lds((AS1 void*)(s + 1536), (AS3 void*)(d + 1536), 16, 0, 0);
  };

  stage(0, 0);
  short8 bfr[8];
#pragma unroll
  for (int j = 0; j < 4; ++j) {
    bfr[j]     = *(const short8*)(Bw + j * 512);
    bfr[4 + j] = *(const short8*)(Bw + 4096 + j * 512);
  }
  int p = 0;
  const int abase = (wm >> 4) * 512;  // u16 offset of this wave's A frags
  for (int it = 0; it < nit; ++it) {
    __syncthreads();
    const bool more = (it + 1 < nit);
    if (more) stage(it + 1, p ^ 1);
    short8 bn[8];
    if (more) {
      const u16* bp = Bw + (size_t)(it + 1) * 8192;
#pragma unroll
      for (int j = 0; j < 4; ++j) {
        bn[j]     = *(const short8*)(bp + j * 512);
        bn[4 + j] = *(const short8*)(bp + 4096 + j * 512);
      }
    }
#pragma unroll
    for (int kk = 0; kk < 2; ++kk) {
      short8 af[4];
#pragma unroll
      for (int i = 0; i < 4; ++i)
        af[i] = *(const short8*)(&As[p][kk * 4096 + abase + i * 512 + lane * 8]);
#pragma unroll
      for (int i = 0; i < 4; ++i)
#pragma unroll
        for (int j = 0; j < 4; ++j)
          acc[i][j] = __builtin_amdgcn_mfma_f32_16x16x32_bf16(af[i], bfr[kk * 4 + j], acc[i][j], 0, 0, 0);
    }
    if (more) {
#pragma unroll
      for (int j = 0; j < 8; ++j) bfr[j] = bn[j];
    }
    p ^= 1;
  }

  const int m0 = by * 128, n0 = bx * 128;
  const size_t zoff = (size_t)blockIdx.z * M * N;
#pragma unroll
  for (int i = 0; i < 4; ++i) {
#pragma unroll
    for (int j = 0; j < 4; ++j) {
#pragma unroll
      for (int r = 0; r < 4; ++r) {
        int row = m0 + wm + i * 16 + quad * 4 + r;
        int col = n0 + wn + j * 16 + l16;
        size_t idx = (size_t)row * N + col;
        float v = acc[i][j][r];
        if constexpr (EPI == 0) {
          ((u16*)OUT)[idx] = f2bf(v);
        } else if constexpr (EPI == 1) {
          ((float*)OUT)[idx] = RES[idx] + v;
        } else if constexpr (EPI == 2) {
          float g = 0.5f * v * (1.0f + erff(v * 0.70710678118654752f));
          const int kb_o = col >> 5, quadp = (col >> 3) & 3, e = col & 7;
          const int mb_o = row >> 7, i_o = (row >> 4) & 7, l16_o = row & 15;
          size_t off = (((size_t)mb_o * (N >> 5) + kb_o) * 8 + i_o) * 512
                       + (quadp * 16 + l16_o) * 8 + e;
          ((u16*)OUT)[off] = f2bf(g);
        } else {
          ((u16*)OUT)[zoff + idx] = f2bf(v);
        }
      }
    }
  }
}

// ---------------- split-K reduce: out = fs + P0 + P1 + P2 + P3 (bf16 P) -----
__global__ void reduce4_kernel(const float* __restrict__ fs,
                               const u16* __restrict__ P,
                               float* __restrict__ out, size_t n) {
  size_t i = ((size_t)blockIdx.x * 256 + threadIdx.x) * 4;
  float4 a = *(const float4*)(fs + i);
  float s[4] = {a.x, a.y, a.z, a.w};
#pragma unroll
  for (int z = 0; z < 4; ++z) {
    ushort4 q = *(const ushort4*)(P + z * n + i);
    s[0] += bf2f(q.x); s[1] += bf2f(q.y); s[2] += bf2f(q.z); s[3] += bf2f(q.w);
  }
  *(float4*)(out + i) = make_float4(s[0], s[1], s[2], s[3]);
}

// ---------------- pack K,V into attention MFMA-fragment order ----------------
__global__ __launch_bounds__(256)
void packkv_kernel(const u16* __restrict__ qkv, u16* __restrict__ Kp,
                   u16* __restrict__ Vp) {
  __shared__ __align__(16) u16 Ks[32][72];
  __shared__ __align__(16) u16 Vs[32][72];
  const int kt = blockIdx.x, h = blockIdx.y, b = blockIdx.z;
  const int tid = threadIdx.x;
  const int key0 = kt * 32;
  {
    const size_t g = (size_t)b * 2048 * 3072 + (size_t)(key0 + (tid >> 3)) * 3072
                     + h * 64 + (tid & 7) * 8;
    *(short8*)(&Ks[tid >> 3][(tid & 7) * 8]) = *(const short8*)(qkv + g + 1024);
    *(short8*)(&Vs[tid >> 3][(tid & 7) * 8]) = *(const short8*)(qkv + g + 2048);
  }
  __syncthreads();
  const int wave = tid >> 6, lane = tid & 63;
  const int quad = lane >> 4, l16 = lane & 15;
  const int permrow = 8 * (l16 >> 2) + (l16 & 3);
  const size_t obase = ((size_t)((b * 16 + h) * 64 + kt)) * 2048 + tid * 8;
  {
    int row = permrow + (wave >> 1) * 4;
    int col = quad * 8 + (wave & 1) * 32;
    *(short8*)(Kp + obase) = *(const short8*)(&Ks[row][col]);
  }
  {
    short8 v;
    int col = wave * 16 + l16;
#pragma unroll
    for (int j = 0; j < 8; ++j) v[j] = (short)Vs[quad * 8 + j][col];
    *(short8*)(Vp + obase) = v;
  }
}

// ---------------- causal flash attention v4 (ctx written A-frag-packed) -----
struct AttnState {
  f32x4 o0, o1, o2, o3;
  float ls;
};

template <bool MASKED>
__device__ __forceinline__ void attn_tile(
    AttnState& st, const u16* kp, const u16* vp, int key0, int q_abs, int quad,
    short8 qf0, short8 qf1) {
  short8 kf00 = *(const short8*)kp;
  short8 kf01 = *(const short8*)(kp + 512);
  short8 kf10 = *(const short8*)(kp + 1024);
  short8 kf11 = *(const short8*)(kp + 1536);
  short8 vf0 = *(const short8*)vp;
  short8 vf1 = *(const short8*)(vp + 512);
  short8 vf2 = *(const short8*)(vp + 1024);
  short8 vf3 = *(const short8*)(vp + 1536);

  f32x4 s0 = {}, s1 = {};
  s0 = __builtin_amdgcn_mfma_f32_16x16x32_bf16(kf00, qf0, s0, 0, 0, 0);
  s0 = __builtin_amdgcn_mfma_f32_16x16x32_bf16(kf01, qf1, s0, 0, 0, 0);
  s1 = __builtin_amdgcn_mfma_f32_16x16x32_bf16(kf10, qf0, s1, 0, 0, 0);
  s1 = __builtin_amdgcn_mfma_f32_16x16x32_bf16(kf11, qf1, s1, 0, 0, 0);

  float p[8];
#pragma unroll
  for (int r = 0; r < 4; ++r) {
    p[r]     = __expf(s0[r]);
    p[4 + r] = __expf(s1[r]);
  }
  if constexpr (MASKED) {
    const int kb = key0 + 8 * quad;
#pragma unroll
    for (int r = 0; r < 4; ++r) {
      if (kb + r > q_abs)     p[r] = 0.f;
      if (kb + 4 + r > q_abs) p[4 + r] = 0.f;
    }
  }
  st.ls += ((p[0] + p[1]) + (p[2] + p[3])) + ((p[4] + p[5]) + (p[6] + p[7]));

  union { u32 u[4]; short8 s; } pu;
  pu.u[0] = permpack(p[0], p[1]);
  pu.u[1] = permpack(p[2], p[3]);
  pu.u[2] = permpack(p[4], p[5]);
  pu.u[3] = permpack(p[6], p[7]);

  st.o0 = __builtin_amdgcn_mfma_f32_16x16x32_bf16(vf0, pu.s, st.o0, 0, 0, 0);
  st.o1 = __builtin_amdgcn_mfma_f32_16x16x32_bf16(vf1, pu.s, st.o1, 0, 0, 0);
  st.o2 = __builtin_amdgcn_mfma_f32_16x16x32_bf16(vf2, pu.s, st.o2, 0, 0, 0);
  st.o3 = __builtin_amdgcn_mfma_f32_16x16x32_bf16(vf3, pu.s, st.o3, 0, 0, 0);
}

__global__ __launch_bounds__(256)
void attn_kernel(const u16* __restrict__ qkv, const u16* __restrict__ Kpack,
                 const u16* __restrict__ Vpack, u16* __restrict__ ctx) {
  const int bx = blockIdx.x, by = blockIdx.y, bz = blockIdx.z;
  const int h = by, b = bz;
  const int qt = ((by >> 3) & 1) ? (31 - bx) : bx;  // per-CU load balance
  const int tid = threadIdx.x, wave = tid >> 6, lane = tid & 63;
  const int quad = lane >> 4, l16 = lane & 15;
  const int q0 = qt * 64;
  const int qrow = q0 + wave * 16;
  const int q_abs = qrow + l16;
  const size_t base = (size_t)b * 2048 * 3072;
  const size_t headoff = (size_t)((b * 16 + h) * 64) * 2048;
  const u16* Kb = Kpack + headoff + lane * 8;
  const u16* Vb = Vpack + headoff + lane * 8;

  short8 qf0, qf1;
  {
    const u16* qp = qkv + base + (size_t)q_abs * 3072 + h * 64 + quad * 8;
    qf0 = *(const short8*)qp;
    qf1 = *(const short8*)(qp + 32);
  }
  AttnState st;
  st.o0 = f32x4{}; st.o1 = f32x4{}; st.o2 = f32x4{}; st.o3 = f32x4{};
  st.ls = 0.f;

  const int nfull = qrow >> 5;
  for (int kt = 0; kt < nfull; ++kt)
    attn_tile<false>(st, Kb + kt * 2048, Vb + kt * 2048, kt * 32, q_abs, quad, qf0, qf1);
  attn_tile<true>(st, Kb + nfull * 2048, Vb + nfull * 2048, nfull * 32, q_abs, quad, qf0, qf1);

  float ls = st.ls;
  ls += __shfl_xor(ls, 16);
  ls += __shfl_xor(ls, 32);
  float inv = 1.0f / ls;

  const int rgl = b * 2048 + q_abs;
  const int mb = rgl >> 7, i_o = (rgl >> 4) & 7;
  f32x4 o[4] = {st.o0, st.o1, st.o2, st.o3};
#pragma unroll
  for (int c = 0; c < 4; ++c) {
    const int c0 = h * 64 + c * 16 + quad * 4;
    const int kb = c0 >> 5, quadp = (c0 >> 3) & 3, e0 = c0 & 7;
    size_t off = (((size_t)mb * 32 + kb) * 8 + i_o) * 512 + (quadp * 16 + l16) * 8 + e0;
    u32 lo = pack2bf(o[c][0] * inv, o[c][1] * inv);
    u32 hi = pack2bf(o[c][2] * inv, o[c][3] * inv);
    *(uint2*)(ctx + off) = make_uint2(lo, hi);
  }
}

// ---------------- launcher ----------------
extern "C" void kernel_launch(void* const* d_in, const int* in_sizes, int n_in,
                              void* d_out, int out_size, void* d_ws, size_t ws_size,
                              hipStream_t stream) {
  const float* x     = (const float*)d_in[0];
  const float* w_qkv = (const float*)d_in[1];
  const float* w_o   = (const float*)d_in[2];
  const float* ln1   = (const float*)d_in[3];
  const float* ln2   = (const float*)d_in[4];
  const float* w1    = (const float*)d_in[5];
  const float* w2    = (const float*)d_in[6];
  float* out = (float*)d_out;

  char* p = (char*)d_ws;
  u16* wqkv_b = (u16*)p; p += (size_t)3072 * 1024 * 2;   // packed B layouts
  u16* wo_b   = (u16*)p; p += (size_t)1024 * 1024 * 2;
  u16* w1_b   = (u16*)p; p += (size_t)4096 * 1024 * 2;
  u16* w2_b   = (u16*)p; p += (size_t)1024 * 4096 * 2;
  u16* h_b    = (u16*)p; p += (size_t)4096 * 1024 * 2;   // packed A (h)
  u16* qkv_b  = (u16*)p;
  u16* g_b    = qkv_b;                                   // packed A (g), aliases qkv+ctx
  p += (size_t)4096 * 3072 * 2;
  u16* ctx_b  = (u16*)p; p += (size_t)4096 * 1024 * 2;   // packed A (ctx)
  float* fs   = (float*)p; p += (size_t)4096 * 1024 * 4;
  // Kpack/Vpack (8 MB each) alias fs (16 MB): dead before fs is written
  u16* kp_b   = (u16*)fs;
  u16* vp_b   = (u16*)fs + (size_t)4 * 1024 * 1024;
  // split-K bf16 partials: 4 x 8 MB after fs (guarded by ws_size)
  u16* Pbuf = (u16*)p;
  const size_t need = (size_t)(p - (char*)d_ws) + (size_t)4 * 4096 * 1024 * 2;
  const bool splitk = ws_size >= need;

  packb_kernel<<<3072, 256, 0, stream>>>(w_qkv, w_o, w1, w2,
                                         wqkv_b, wo_b, w1_b, w2_b);

  rmsnorm_kernel<<<4096, 256, 0, stream>>>(x, ln1, h_b);
  gemm_pp<0><<<dim3(24, 32, 1), 256, 0, stream>>>(h_b, wqkv_b, nullptr, qkv_b, 4096, 3072, 1024, 1024);
  packkv_kernel<<<dim3(64, 16, 2), 256, 0, stream>>>(qkv_b, kp_b, vp_b);
  attn_kernel<<<dim3(32, 16, 2), 256, 0, stream>>>(qkv_b, kp_b, vp_b, ctx_b);
  gemm_pp<1><<<dim3(8, 32, 1), 256, 0, stream>>>(ctx_b, wo_b, x, fs, 4096, 1024, 1024, 1024);
  rmsnorm_kernel<<<4096, 256, 0, stream>>>(fs, ln2, h_b);
  gemm_pp<2><<<dim3(32, 32, 1), 256, 0, stream>>>(h_b, w1_b, nullptr, g_b, 4096, 4096, 1024, 1024);
  if (splitk) {
    gemm_pp<3><<<dim3(8, 32, 4), 256, 0, stream>>>(g_b, w2_b, nullptr, Pbuf, 4096, 1024, 4096, 1024);
    reduce4_kernel<<<4096, 256, 0, stream>>>(fs, Pbuf, out, (size_t)4096 * 1024);
  } else {
    gemm_pp<1><<<dim3(8, 32, 1), 256, 0, stream>>>(g_b, w2_b, fs, out, 4096, 1024, 4096, 4096);
  }
}

// Round 12
// 319.951 us; speedup vs baseline: 1.0293x; 1.0293x over previous
//
#include <hip/hip_runtime.h>

typedef unsigned short u16;
typedef unsigned int u32;
typedef __attribute__((ext_vector_type(8))) short short8;
typedef __attribute__((ext_vector_type(4))) float f32x4;

#define AS1 __attribute__((address_space(1)))
#define AS3 __attribute__((address_space(3)))

__device__ __forceinline__ u16 f2bf(float f) {
  union { float f; unsigned u; } v; v.f = f;
  return (u16)((v.u + 0x7fffu + ((v.u >> 16) & 1u)) >> 16);
}
__device__ __forceinline__ u32 pack2bf(float a, float b) {
  return (u32)f2bf(a) | ((u32)f2bf(b) << 16);
}
__device__ __forceinline__ float bf2f(u16 h) {
  union { u32 u; float f; } v; v.u = ((u32)h) << 16; return v.f;
}
// truncating bf16 pack: [b.hi16 : a.hi16] in one v_perm_b32
__device__ __forceinline__ u32 permpack(float a, float b) {
  union { float f; u32 u; } ua, ub; ua.f = a; ub.f = b;
  return __builtin_amdgcn_perm(ub.u, ua.u, 0x07060302u);
}

// Fragment-packed matrix layout (both GEMM operands):
// per (rb, kb): 8 frags x 512 u16; frag f, slot lane*8+e =
//   X[rb*128 + f*16 + (lane&15)][kb*32 + (lane>>4)*8 + e]
// One frag = one contiguous 1KB b128 burst at base+lane*8.
// A 32-K tile of a row-block = 8 KB CONTIGUOUS -> glds staging is dense lines;
// LDS frag reads are contiguous lane*16 (conflict-free by construction).

// ---------------- pack weights fp32 -> bf16, frag order ----------------
__global__ __launch_bounds__(256)
void packb_kernel(const float* __restrict__ wqkv, const float* __restrict__ wo,
                  const float* __restrict__ w1, const float* __restrict__ w2,
                  u16* __restrict__ oqkv, u16* __restrict__ oo,
                  u16* __restrict__ o1, u16* __restrict__ o2) {
  __shared__ u16 Ls[128][40];
  const int b = blockIdx.x, t = threadIdx.x;
  const float* W; u16* O; int nb, kb, KB; float scale = 1.0f;
  if (b < 768)       { W = wqkv; O = oqkv; KB = 32;  int i2 = b;        nb = i2 >> 5; kb = i2 & 31;
                       if (nb >= 8 && nb < 16) scale = 0.125f; }
  else if (b < 1024) { W = wo;   O = oo;   KB = 32;  int i2 = b - 768;  nb = i2 >> 5; kb = i2 & 31; }
  else if (b < 2048) { W = w1;   O = o1;   KB = 32;  int i2 = b - 1024; nb = i2 >> 5; kb = i2 & 31; }
  else               { W = w2;   O = o2;   KB = 128; int i2 = b - 2048; nb = i2 >> 7; kb = i2 & 127; }
  const int K = KB * 32;
  {
    const int r = t >> 1, c0 = (t & 1) * 16;
    const float* src = W + (size_t)(nb * 128 + r) * K + kb * 32 + c0;
#pragma unroll
    for (int e = 0; e < 16; ++e) Ls[r][c0 + e] = f2bf(src[e] * scale);
  }
  __syncthreads();
  const int f = t >> 5, l0 = (t & 31) * 2;
  u16* dst = O + ((size_t)(nb * KB + kb) * 8 + f) * 512 + (size_t)l0 * 8;
  short8 v0, v1;
#pragma unroll
  for (int e = 0; e < 8; ++e) v0[e] = (short)Ls[f * 16 + (l0 & 15)][(l0 >> 4) * 8 + e];
  const int l1 = l0 + 1;
#pragma unroll
  for (int e = 0; e < 8; ++e) v1[e] = (short)Ls[f * 16 + (l1 & 15)][(l1 >> 4) * 8 + e];
  *(short8*)dst = v0;
  *(short8*)(dst + 8) = v1;
}

// ---------------- RMSNorm: fp32 in -> bf16 A-frag-packed out (D=1024) -------
__global__ void rmsnorm_kernel(const float* __restrict__ x, const float* __restrict__ w,
                               u16* __restrict__ out) {
  const int row = blockIdx.x, tid = threadIdx.x;
  const float4 v = ((const float4*)(x + (size_t)row * 1024))[tid];
  float ss = v.x * v.x + v.y * v.y + v.z * v.z + v.w * v.w;
#pragma unroll
  for (int off = 32; off > 0; off >>= 1) ss += __shfl_xor(ss, off);
  __shared__ float red[4];
  if ((tid & 63) == 0) red[tid >> 6] = ss;
  __syncthreads();
  float tot = red[0] + red[1] + red[2] + red[3];
  float scale = 1.0f / sqrtf(tot * (1.0f / 1024.0f) + 1e-5f);
  const float4 wv = ((const float4*)w)[tid];
  const int kb = tid >> 3, quadp = (tid >> 1) & 3, e0 = (tid & 1) * 4;
  const int mb = row >> 7, i_o = (row >> 4) & 7, l16_o = row & 15;
  size_t off = (((size_t)mb * 32 + kb) * 8 + i_o) * 512 + (quadp * 16 + l16_o) * 8 + e0;
  u32 lo = pack2bf(v.x * scale * wv.x, v.y * scale * wv.y);
  u32 hi = pack2bf(v.z * scale * wv.z, v.w * scale * wv.w);
  *(uint2*)(out + off) = make_uint2(lo, hi);
}

// ---------------- GEMM v5: R9 cadence, packed-A staging ----------------
// EPI 0: store bf16 row-major        EPI 1: out_f32 = RES + C (row-major)
// EPI 2: store bf16(gelu(C)) PACKED  EPI 3: bf16 partial row-major (split-K)
// BK=32, 2x8KB LDS dbuf for A (contiguous 8KB frag-packed region per iter ->
// dense glds lines, conflict-free lane*16 ds_read_b128, zero address math),
// direct packed-B 4-frag register prefetch one iter ahead, peeled last iter.
template <int EPI>
__global__ __launch_bounds__(256, 3)
void gemm_pp(const u16* __restrict__ Ap, const u16* __restrict__ Bp,
             const float* __restrict__ RES, void* __restrict__ OUT,
             int M, int N, int K, int KS) {
  __shared__ __align__(16) u16 As[2][4096];   // 2 x 8 KB
  const int tid = threadIdx.x;
  const int wave = tid >> 6, lane = tid & 63;
  const int quad = lane >> 4, l16 = lane & 15;
  int bx = blockIdx.x, by = blockIdx.y;
  const int gx = gridDim.x, gy = gridDim.y;
  if (((gx & 1) | (gy & 3)) == 0) {          // XCD-region remap (R9)
    const int lin = blockIdx.x + gx * blockIdx.y;
    const int xcd = lin & 7, j = lin >> 3;
    const int rw = gx >> 1;
    bx = (xcd & 1) * rw + j % rw;
    by = (xcd >> 1) * (gy >> 2) + j / rw;
  }
  const int wm = (wave >> 1) * 64, wn = (wave & 1) * 64;
  const int KB = K >> 5;
  f32x4 acc[4][4] = {};

  const int kb0 = (blockIdx.z * KS) >> 5;
  const int nit = KS >> 5;                    // 32-K iterations
  // A: contiguous 8KB tile per iter; each wave stages its 2KB quarter
  const u16* Ag = Ap + ((size_t)by * KB + kb0) * 4096 + wave * 1024 + lane * 8;
  // B: direct packed frags (wn selects frag group)
  const u16* Bw = Bp + (((size_t)bx * KB + kb0) * 8 + (wn >> 4)) * 512 + (size_t)lane * 8;

  auto stage = [&](int it, int pp) {
    const u16* s = Ag + (size_t)it * 4096;
    u16* d = &As[pp][wave * 1024];
    __builtin_amdgcn_global_load_lds((AS1 void*)s, (AS3 void*)d, 16, 0, 0);
    __builtin_amdgcn_global_load_lds((AS1 void*)(s + 512), (AS3 void*)(d + 512), 16, 0, 0);
  };

  stage(0, 0);
  short8 bfr[4];
#pragma unroll
  for (int j = 0; j < 4; ++j) bfr[j] = *(const short8*)(Bw + j * 512);
  int p = 0;
  const int abase = (wm >> 4) * 512;          // u16 offset of this wave's A frags
  for (int it = 0; it < nit - 1; ++it) {
    __syncthreads();
    stage(it + 1, p ^ 1);
    short8 bn[4];
    {
      const u16* bp = Bw + (size_t)(it + 1) * 4096;
#pragma unroll
      for (int j = 0; j < 4; ++j) bn[j] = *(const short8*)(bp + j * 512);
    }
    short8 af[4];
#pragma unroll
    for (int i = 0; i < 4; ++i)
      af[i] = *(const short8*)(&As[p][abase + i * 512 + lane * 8]);
#pragma unroll
    for (int i = 0; i < 4; ++i)
#pragma unroll
      for (int j = 0; j < 4; ++j)
        acc[i][j] = __builtin_amdgcn_mfma_f32_16x16x32_bf16(af[i], bfr[j], acc[i][j], 0, 0, 0);
#pragma unroll
    for (int j = 0; j < 4; ++j) bfr[j] = bn[j];
    p ^= 1;
  }
  {  // peeled last iteration
    __syncthreads();
    short8 af[4];
#pragma unroll
    for (int i = 0; i < 4; ++i)
      af[i] = *(const short8*)(&As[p][abase + i * 512 + lane * 8]);
#pragma unroll
    for (int i = 0; i < 4; ++i)
#pragma unroll
      for (int j = 0; j < 4; ++j)
        acc[i][j] = __builtin_amdgcn_mfma_f32_16x16x32_bf16(af[i], bfr[j], acc[i][j], 0, 0, 0);
  }

  const int m0 = by * 128, n0 = bx * 128;
  const size_t zoff = (size_t)blockIdx.z * M * N;
#pragma unroll
  for (int i = 0; i < 4; ++i) {
#pragma unroll
    for (int j = 0; j < 4; ++j) {
#pragma unroll
      for (int r = 0; r < 4; ++r) {
        int row = m0 + wm + i * 16 + quad * 4 + r;
        int col = n0 + wn + j * 16 + l16;
        size_t idx = (size_t)row * N + col;
        float v = acc[i][j][r];
        if constexpr (EPI == 0) {
          ((u16*)OUT)[idx] = f2bf(v);
        } else if constexpr (EPI == 1) {
          ((float*)OUT)[idx] = RES[idx] + v;
        } else if constexpr (EPI == 2) {
          float g = 0.5f * v * (1.0f + erff(v * 0.70710678118654752f));
          const int kb_o = col >> 5, quadp = (col >> 3) & 3, e = col & 7;
          const int mb_o = row >> 7, i_o = (row >> 4) & 7, l16_o = row & 15;
          size_t off = (((size_t)mb_o * (N >> 5) + kb_o) * 8 + i_o) * 512
                       + (quadp * 16 + l16_o) * 8 + e;
          ((u16*)OUT)[off] = f2bf(g);
        } else {
          ((u16*)OUT)[zoff + idx] = f2bf(v);
        }
      }
    }
  }
}

// ---------------- split-K reduce: out = fs + P0 + P1 + P2 + P3 (bf16 P) -----
__global__ void reduce4_kernel(const float* __restrict__ fs,
                               const u16* __restrict__ P,
                               float* __restrict__ out, size_t n) {
  size_t i = ((size_t)blockIdx.x * 256 + threadIdx.x) * 4;
  float4 a = *(const float4*)(fs + i);
  float s[4] = {a.x, a.y, a.z, a.w};
#pragma unroll
  for (int z = 0; z < 4; ++z) {
    ushort4 q = *(const ushort4*)(P + z * n + i);
    s[0] += bf2f(q.x); s[1] += bf2f(q.y); s[2] += bf2f(q.z); s[3] += bf2f(q.w);
  }
  *(float4*)(out + i) = make_float4(s[0], s[1], s[2], s[3]);
}

// ---------------- pack K,V into attention MFMA-fragment order ----------------
__global__ __launch_bounds__(256)
void packkv_kernel(const u16* __restrict__ qkv, u16* __restrict__ Kp,
                   u16* __restrict__ Vp) {
  __shared__ __align__(16) u16 Ks[32][72];
  __shared__ __align__(16) u16 Vs[32][72];
  const int kt = blockIdx.x, h = blockIdx.y, b = blockIdx.z;
  const int tid = threadIdx.x;
  const int key0 = kt * 32;
  {
    const size_t g = (size_t)b * 2048 * 3072 + (size_t)(key0 + (tid >> 3)) * 3072
                     + h * 64 + (tid & 7) * 8;
    *(short8*)(&Ks[tid >> 3][(tid & 7) * 8]) = *(const short8*)(qkv + g + 1024);
    *(short8*)(&Vs[tid >> 3][(tid & 7) * 8]) = *(const short8*)(qkv + g + 2048);
  }
  __syncthreads();
  const int wave = tid >> 6, lane = tid & 63;
  const int quad = lane >> 4, l16 = lane & 15;
  const int permrow = 8 * (l16 >> 2) + (l16 & 3);
  const size_t obase = ((size_t)((b * 16 + h) * 64 + kt)) * 2048 + tid * 8;
  {
    int row = permrow + (wave >> 1) * 4;
    int col = quad * 8 + (wave & 1) * 32;
    *(short8*)(Kp + obase) = *(const short8*)(&Ks[row][col]);
  }
  {
    short8 v;
    int col = wave * 16 + l16;
#pragma unroll
    for (int j = 0; j < 8; ++j) v[j] = (short)Vs[quad * 8 + j][col];
    *(short8*)(Vp + obase) = v;
  }
}

// ---------------- causal flash attention v4 (ctx written A-frag-packed) -----
struct AttnState {
  f32x4 o0, o1, o2, o3;
  float ls;
};

template <bool MASKED>
__device__ __forceinline__ void attn_tile(
    AttnState& st, const u16* kp, const u16* vp, int key0, int q_abs, int quad,
    short8 qf0, short8 qf1) {
  short8 kf00 = *(const short8*)kp;
  short8 kf01 = *(const short8*)(kp + 512);
  short8 kf10 = *(const short8*)(kp + 1024);
  short8 kf11 = *(const short8*)(kp + 1536);
  short8 vf0 = *(const short8*)vp;
  short8 vf1 = *(const short8*)(vp + 512);
  short8 vf2 = *(const short8*)(vp + 1024);
  short8 vf3 = *(const short8*)(vp + 1536);

  f32x4 s0 = {}, s1 = {};
  s0 = __builtin_amdgcn_mfma_f32_16x16x32_bf16(kf00, qf0, s0, 0, 0, 0);
  s0 = __builtin_amdgcn_mfma_f32_16x16x32_bf16(kf01, qf1, s0, 0, 0, 0);
  s1 = __builtin_amdgcn_mfma_f32_16x16x32_bf16(kf10, qf0, s1, 0, 0, 0);
  s1 = __builtin_amdgcn_mfma_f32_16x16x32_bf16(kf11, qf1, s1, 0, 0, 0);

  float p[8];
#pragma unroll
  for (int r = 0; r < 4; ++r) {
    p[r]     = __expf(s0[r]);
    p[4 + r] = __expf(s1[r]);
  }
  if constexpr (MASKED) {
    const int kb = key0 + 8 * quad;
#pragma unroll
    for (int r = 0; r < 4; ++r) {
      if (kb + r > q_abs)     p[r] = 0.f;
      if (kb + 4 + r > q_abs) p[4 + r] = 0.f;
    }
  }
  st.ls += ((p[0] + p[1]) + (p[2] + p[3])) + ((p[4] + p[5]) + (p[6] + p[7]));

  union { u32 u[4]; short8 s; } pu;
  pu.u[0] = permpack(p[0], p[1]);
  pu.u[1] = permpack(p[2], p[3]);
  pu.u[2] = permpack(p[4], p[5]);
  pu.u[3] = permpack(p[6], p[7]);

  st.o0 = __builtin_amdgcn_mfma_f32_16x16x32_bf16(vf0, pu.s, st.o0, 0, 0, 0);
  st.o1 = __builtin_amdgcn_mfma_f32_16x16x32_bf16(vf1, pu.s, st.o1, 0, 0, 0);
  st.o2 = __builtin_amdgcn_mfma_f32_16x16x32_bf16(vf2, pu.s, st.o2, 0, 0, 0);
  st.o3 = __builtin_amdgcn_mfma_f32_16x16x32_bf16(vf3, pu.s, st.o3, 0, 0, 0);
}

__global__ __launch_bounds__(256)
void attn_kernel(const u16* __restrict__ qkv, const u16* __restrict__ Kpack,
                 const u16* __restrict__ Vpack, u16* __restrict__ ctx) {
  const int bx = blockIdx.x, by = blockIdx.y, bz = blockIdx.z;
  const int h = by, b = bz;
  const int qt = ((by >> 3) & 1) ? (31 - bx) : bx;  // per-CU load balance
  const int tid = threadIdx.x, wave = tid >> 6, lane = tid & 63;
  const int quad = lane >> 4, l16 = lane & 15;
  const int q0 = qt * 64;
  const int qrow = q0 + wave * 16;
  const int q_abs = qrow + l16;
  const size_t base = (size_t)b * 2048 * 3072;
  const size_t headoff = (size_t)((b * 16 + h) * 64) * 2048;
  const u16* Kb = Kpack + headoff + lane * 8;
  const u16* Vb = Vpack + headoff + lane * 8;

  short8 qf0, qf1;
  {
    const u16* qp = qkv + base + (size_t)q_abs * 3072 + h * 64 + quad * 8;
    qf0 = *(const short8*)qp;
    qf1 = *(const short8*)(qp + 32);
  }
  AttnState st;
  st.o0 = f32x4{}; st.o1 = f32x4{}; st.o2 = f32x4{}; st.o3 = f32x4{};
  st.ls = 0.f;

  const int nfull = qrow >> 5;
  for (int kt = 0; kt < nfull; ++kt)
    attn_tile<false>(st, Kb + kt * 2048, Vb + kt * 2048, kt * 32, q_abs, quad, qf0, qf1);
  attn_tile<true>(st, Kb + nfull * 2048, Vb + nfull * 2048, nfull * 32, q_abs, quad, qf0, qf1);

  float ls = st.ls;
  ls += __shfl_xor(ls, 16);
  ls += __shfl_xor(ls, 32);
  float inv = 1.0f / ls;

  const int rgl = b * 2048 + q_abs;
  const int mb = rgl >> 7, i_o = (rgl >> 4) & 7;
  f32x4 o[4] = {st.o0, st.o1, st.o2, st.o3};
#pragma unroll
  for (int c = 0; c < 4; ++c) {
    const int c0 = h * 64 + c * 16 + quad * 4;
    const int kb = c0 >> 5, quadp = (c0 >> 3) & 3, e0 = c0 & 7;
    size_t off = (((size_t)mb * 32 + kb) * 8 + i_o) * 512 + (quadp * 16 + l16) * 8 + e0;
    u32 lo = pack2bf(o[c][0] * inv, o[c][1] * inv);
    u32 hi = pack2bf(o[c][2] * inv, o[c][3] * inv);
    *(uint2*)(ctx + off) = make_uint2(lo, hi);
  }
}

// ---------------- launcher ----------------
extern "C" void kernel_launch(void* const* d_in, const int* in_sizes, int n_in,
                              void* d_out, int out_size, void* d_ws, size_t ws_size,
                              hipStream_t stream) {
  const float* x     = (const float*)d_in[0];
  const float* w_qkv = (const float*)d_in[1];
  const float* w_o   = (const float*)d_in[2];
  const float* ln1   = (const float*)d_in[3];
  const float* ln2   = (const float*)d_in[4];
  const float* w1    = (const float*)d_in[5];
  const float* w2    = (const float*)d_in[6];
  float* out = (float*)d_out;

  char* p = (char*)d_ws;
  u16* wqkv_b = (u16*)p; p += (size_t)3072 * 1024 * 2;   // packed B layouts
  u16* wo_b   = (u16*)p; p += (size_t)1024 * 1024 * 2;
  u16* w1_b   = (u16*)p; p += (size_t)4096 * 1024 * 2;
  u16* w2_b   = (u16*)p; p += (size_t)1024 * 4096 * 2;
  u16* h_b    = (u16*)p; p += (size_t)4096 * 1024 * 2;   // packed A (h)
  u16* qkv_b  = (u16*)p;
  u16* g_b    = qkv_b;                                   // packed A (g), aliases qkv+ctx
  p += (size_t)4096 * 3072 * 2;
  u16* ctx_b  = (u16*)p; p += (size_t)4096 * 1024 * 2;   // packed A (ctx)
  float* fs   = (float*)p; p += (size_t)4096 * 1024 * 4;
  // Kpack/Vpack (8 MB each) alias fs (16 MB): dead before fs is written
  u16* kp_b   = (u16*)fs;
  u16* vp_b   = (u16*)fs + (size_t)4 * 1024 * 1024;
  // split-K bf16 partials: 4 x 8 MB after fs (guarded by ws_size)
  u16* Pbuf = (u16*)p;
  const size_t need = (size_t)(p - (char*)d_ws) + (size_t)4 * 4096 * 1024 * 2;
  const bool splitk = ws_size >= need;

  packb_kernel<<<3072, 256, 0, stream>>>(w_qkv, w_o, w1, w2,
                                         wqkv_b, wo_b, w1_b, w2_b);

  rmsnorm_kernel<<<4096, 256, 0, stream>>>(x, ln1, h_b);
  gemm_pp<0><<<dim3(24, 32, 1), 256, 0, stream>>>(h_b, wqkv_b, nullptr, qkv_b, 4096, 3072, 1024, 1024);
  packkv_kernel<<<dim3(64, 16, 2), 256, 0, stream>>>(qkv_b, kp_b, vp_b);
  attn_kernel<<<dim3(32, 16, 2), 256, 0, stream>>>(qkv_b, kp_b, vp_b, ctx_b);
  gemm_pp<1><<<dim3(8, 32, 1), 256, 0, stream>>>(ctx_b, wo_b, x, fs, 4096, 1024, 1024, 1024);
  rmsnorm_kernel<<<4096, 256, 0, stream>>>(fs, ln2, h_b);
  gemm_pp<2><<<dim3(32, 32, 1), 256, 0, stream>>>(h_b, w1_b, nullptr, g_b, 4096, 4096, 1024, 1024);
  if (splitk) {
    gemm_pp<3><<<dim3(8, 32, 4), 256, 0, stream>>>(g_b, w2_b, nullptr, Pbuf, 4096, 1024, 4096, 1024);
    reduce4_kernel<<<4096, 256, 0, stream>>>(fs, Pbuf, out, (size_t)4096 * 1024);
  } else {
    gemm_pp<1><<<dim3(8, 32, 1), 256, 0, stream>>>(g_b, w2_b, fs, out, 4096, 1024, 4096, 4096);
  }
}